// Round 1
// baseline (550.756 us; speedup 1.0000x reference)
//
#include <hip/hip_runtime.h>

#define NSTEP 730
#define NGRID 1000
#define MU    8
#define NPAR  13
#define PRECS 1e-5f

// element strides in `parameters` (NSTEP, NGRID, 13, MU):
//   idx(t,g,i,m) = t*104000 + g*104 + i*8 + m
#define PAR_TSTRIDE 104000u
#define PAR_GSTRIDE 104u
// x (NSTEP, NGRID, 3): idx(t,g,c) = t*3000 + g*3 + c
#define X_TSTRIDE 3000u

constexpr float LB_[NPAR] = {1.0f, 50.0f, 0.05f, 0.01f, 0.001f, 0.2f, 0.0f,
                             0.0f, -2.5f, 0.5f, 0.0f, 0.0f, 0.3f};
constexpr float UB_[NPAR] = {6.0f, 1000.0f, 0.9f, 0.5f, 0.2f, 1.0f, 10.0f,
                             100.0f, 2.5f, 10.0f, 0.1f, 0.2f, 5.0f};

__device__ __forceinline__ float fast_rcp(float x)  { return __builtin_amdgcn_rcpf(x); }
__device__ __forceinline__ float fast_exp2(float x) { return __builtin_amdgcn_exp2f(x); }
__device__ __forceinline__ float fast_log2(float x) { return __builtin_amdgcn_logf(x); }
__device__ __forceinline__ float clamp01(float v)   { return fminf(fmaxf(v, 0.f), 1.f); }

__device__ __forceinline__ int mod13(int v) {
    int r = v % NPAR;
    if (r < 0) r += NPAR;
    return r;
}

// One HBV step on scalar state. Returns Q.
__device__ __forceinline__ float hbv_step(
    float P_, float T_, float ET_,
    float BETA, float FC, float K0, float K1, float K2, float LP,
    float PERCc, float UZL, float TT, float CFMAX, float CFR, float CWH,
    float BETAET,
    float& SP, float& MW, float& SM, float& SUZ, float& SLZ)
{
    float dT    = T_ - TT;
    float RAIN  = (T_ >= TT) ? P_ : 0.f;
    float SNOW  = P_ - RAIN;
    SP += SNOW;
    float cm    = CFMAX * dT;
    float melt  = fminf(fmaxf(cm, 0.f), SP);
    MW += melt; SP -= melt;
    float refr  = fminf(fmaxf(-CFR * cm, 0.f), MW);
    SP += refr; MW -= refr;
    float tosoil = fmaxf(MW - CWH * SP, 0.f);
    MW -= tosoil;
    float wetr   = SM * fast_rcp(FC);
    float soilw  = clamp01(fast_exp2(BETA * fast_log2(wetr)));
    float rt     = RAIN + tosoil;
    float rech   = rt * soilw;
    SM += rt - rech;
    float excess = fmaxf(SM - FC, 0.f);
    SM -= excess;
    float er     = SM * fast_rcp(LP * FC);
    float evapf  = clamp01(fast_exp2(BETAET * fast_log2(er)));
    float ETact  = fminf(SM, ET_ * evapf);
    SM = fmaxf(SM - ETact, PRECS);
    SUZ += rech + excess;
    float PERC = fminf(SUZ, PERCc);
    SUZ -= PERC;
    float Q0 = K0 * fmaxf(SUZ - UZL, 0.f);
    SUZ -= Q0;
    float Q1 = K1 * SUZ;
    SUZ -= Q1;
    SLZ += PERC;
    float Q2 = K2 * SLZ;
    SLZ -= Q2;
    return Q0 + Q1 + Q2;
}

// Fast path: NTD (number of time-varying param indices) is a template constant.
// One lane per (grid, mu) chain. Group-of-G double-buffered register prefetch.
template <int NTD>
__global__ __launch_bounds__(64, 1) void hbv_scan(
    const float* __restrict__ x, const float* __restrict__ par,
    const int* __restrict__ staind_p, const int* __restrict__ tdlst_p,
    float* __restrict__ out)
{
    constexpr int G  = 10;         // steps per prefetch group (730 = 73*10)
    constexpr int NG = NSTEP / G;  // 73

    const int tid = blockIdx.x * 64 + threadIdx.x;
    const int g   = tid >> 3;   // MU = 8
    const int m   = tid & 7;
    if (g >= NGRID) return;

    const int staind = staind_p[0];

    // Time-varying indices + routing selectors (all wave-uniform).
    int      idxv[NTD];
    unsigned offv[NTD];
    float    lbv[NTD], dvv[NTD];
    float    selv[NTD][NPAR];
#pragma unroll
    for (int jj = 0; jj < NTD; ++jj) {
        int v    = mod13(tdlst_p[jj] - 1);
        idxv[jj] = v;
        offv[jj] = (unsigned)v * MU;
        float lb = 0.f, ub = 0.f;
#pragma unroll
        for (int i = 0; i < NPAR; ++i)
            if (v == i) { lb = LB_[i]; ub = UB_[i]; }
        lbv[jj] = lb; dvv[jj] = ub - lb;
        bool dup = false;
#pragma unroll
        for (int jk = 0; jk < NTD; ++jk)
            if (jk < jj && idxv[jk] == v) dup = true;
#pragma unroll
        for (int i = 0; i < NPAR; ++i)
            selv[jj][i] = (!dup && v == i) ? 1.f : 0.f;
    }

    const unsigned cpar = (unsigned)g * PAR_GSTRIDE + (unsigned)m;
    const unsigned g3   = (unsigned)g * 3u;

    // Fixed (staind-row) params, scaled, pre-blended: base_i = fix_i*(1 - sum sel)
    float basep[NPAR];
#pragma unroll
    for (int i = 0; i < NPAR; ++i) {
        float raw = par[(unsigned)staind * PAR_TSTRIDE + cpar + (unsigned)i * MU];
        float fx  = LB_[i] + raw * (UB_[i] - LB_[i]);
        float w   = 1.f;
#pragma unroll
        for (int jj = 0; jj < NTD; ++jj) w -= selv[jj][i];
        basep[i] = fx * w;
    }

    // Double-buffered register prefetch.
    float bS[2][NTD][G];
    float bP[2][G], bT[2][G], bE[2][G];

    auto load_group = [&](float (&S)[NTD][G], float (&P)[G], float (&T)[G],
                          float (&E)[G], int t0) {
#pragma unroll
        for (int j = 0; j < G; ++j) {
            unsigned t  = (unsigned)(t0 + j);
            unsigned xo = t * X_TSTRIDE + g3;
            P[j] = x[xo];
            T[j] = x[xo + 1u];
            E[j] = x[xo + 2u];
            unsigned po = t * PAR_TSTRIDE + cpar;
#pragma unroll
            for (int jj = 0; jj < NTD; ++jj) S[jj][j] = par[po + offv[jj]];
        }
    };

    float SP = 0.001f, MW = 0.001f, SM = 0.001f, SUZ = 0.001f, SLZ = 0.001f;

    auto compute_group = [&](const float (&S)[NTD][G], const float (&P)[G],
                             const float (&T)[G], const float (&E)[G], int t0) {
#pragma unroll
        for (int j = 0; j < G; ++j) {
            // scale the time-varying raw values
            float sv[NTD];
#pragma unroll
            for (int jj = 0; jj < NTD; ++jj)
                sv[jj] = fmaf(S[jj][j], dvv[jj], lbv[jj]);
            // route into the 13 named params (branch-free, uniform selectors)
            float pr[NPAR];
#pragma unroll
            for (int i = 0; i < NPAR; ++i) {
                float v = basep[i];
#pragma unroll
                for (int jj = 0; jj < NTD; ++jj) v = fmaf(selv[jj][i], sv[jj], v);
                pr[i] = v;
            }
            float q = hbv_step(P[j], T[j], E[j],
                               pr[0], pr[1], pr[2], pr[3], pr[4], pr[5], pr[6],
                               pr[7], pr[8], pr[9], pr[10], pr[11], pr[12],
                               SP, MW, SM, SUZ, SLZ);
            // mean over mu (8 consecutive lanes)
            q += __shfl_xor(q, 1);
            q += __shfl_xor(q, 2);
            q += __shfl_xor(q, 4);
            if (m == 0) out[(unsigned)(t0 + j) * (unsigned)NGRID + (unsigned)g] = q * 0.125f;
        }
    };

    load_group(bS[0], bP[0], bT[0], bE[0], 0);
    for (int gp = 0; gp < NG; gp += 2) {
        if (gp + 1 < NG) load_group(bS[1], bP[1], bT[1], bE[1], (gp + 1) * G);
        compute_group(bS[0], bP[0], bT[0], bE[0], gp * G);
        if (gp + 2 < NG) load_group(bS[0], bP[0], bT[0], bE[0], (gp + 2) * G);
        if (gp + 1 < NG) compute_group(bS[1], bP[1], bT[1], bE[1], (gp + 1) * G);
    }
}

// Generic fallback for arbitrary n_td: per-step loads of all 13 params via
// stride trick (stride 0 for fixed -> L1 hits). Correct but unpipelined.
__global__ __launch_bounds__(64, 1) void hbv_scan_generic(
    const float* __restrict__ x, const float* __restrict__ par,
    const int* __restrict__ staind_p, const int* __restrict__ tdlst_p,
    int n_td, float* __restrict__ out)
{
    const int tid = blockIdx.x * 64 + threadIdx.x;
    const int g   = tid >> 3;
    const int m   = tid & 7;
    if (g >= NGRID) return;

    const int staind    = staind_p[0];
    const unsigned cpar = (unsigned)g * PAR_GSTRIDE + (unsigned)m;
    const unsigned g3   = (unsigned)g * 3u;

    unsigned off[NPAR], st[NPAR];
#pragma unroll
    for (int i = 0; i < NPAR; ++i) {
        bool vr = false;
        for (int j = 0; j < n_td; ++j) {
            if (mod13(tdlst_p[j] - 1) == i) vr = true;
        }
        off[i] = (vr ? 0u : (unsigned)staind * PAR_TSTRIDE) + cpar + (unsigned)i * MU;
        st[i]  = vr ? PAR_TSTRIDE : 0u;
    }

    float SP = 0.001f, MW = 0.001f, SM = 0.001f, SUZ = 0.001f, SLZ = 0.001f;

    for (int t = 0; t < NSTEP; ++t) {
        unsigned xo = (unsigned)t * X_TSTRIDE + g3;
        float P_ = x[xo], T_ = x[xo + 1u], E_ = x[xo + 2u];
        float pr[NPAR];
#pragma unroll
        for (int i = 0; i < NPAR; ++i) {
            float raw = par[off[i]];
            off[i] += st[i];
            pr[i] = LB_[i] + raw * (UB_[i] - LB_[i]);
        }
        float q = hbv_step(P_, T_, E_,
                           pr[0], pr[1], pr[2], pr[3], pr[4], pr[5], pr[6],
                           pr[7], pr[8], pr[9], pr[10], pr[11], pr[12],
                           SP, MW, SM, SUZ, SLZ);
        q += __shfl_xor(q, 1);
        q += __shfl_xor(q, 2);
        q += __shfl_xor(q, 4);
        if (m == 0) out[(unsigned)t * (unsigned)NGRID + (unsigned)g] = q * 0.125f;
    }
}

extern "C" void kernel_launch(void* const* d_in, const int* in_sizes, int n_in,
                              void* d_out, int out_size, void* d_ws, size_t ws_size,
                              hipStream_t stream) {
    const float* x      = (const float*)d_in[0];
    const float* par    = (const float*)d_in[1];
    const int*   staind = (const int*)d_in[2];
    const int*   tdlst  = (const int*)d_in[3];
    float*       out    = (float*)d_out;
    const int n_td = in_sizes[3];

    const int threads = NGRID * MU;            // 8000
    const int block   = 64;
    const int grid    = (threads + block - 1) / block;  // 125

    switch (n_td) {
        case 1: hbv_scan<1><<<grid, block, 0, stream>>>(x, par, staind, tdlst, out); break;
        case 2: hbv_scan<2><<<grid, block, 0, stream>>>(x, par, staind, tdlst, out); break;
        case 3: hbv_scan<3><<<grid, block, 0, stream>>>(x, par, staind, tdlst, out); break;
        case 4: hbv_scan<4><<<grid, block, 0, stream>>>(x, par, staind, tdlst, out); break;
        default:
            hbv_scan_generic<<<grid, block, 0, stream>>>(x, par, staind, tdlst, n_td, out);
            break;
    }
}

// Round 3
// 469.673 us; speedup vs baseline: 1.1726x; 1.1726x over previous
//
#include <hip/hip_runtime.h>

#define NSTEP 730
#define NGRID 1000
#define MU    8
#define NPAR  13
#define PRECS 1e-5f

// parameters (NSTEP, NGRID, 13, MU): idx(t,g,i,m) = t*104000 + g*104 + i*8 + m
#define PAR_TSTRIDE 104000u
#define PAR_GSTRIDE 104u
// x (NSTEP, NGRID, 3): idx(t,g,c) = t*3000 + g*3 + c
#define X_TSTRIDE 3000u

#define GSTEPS 10                // steps per prefetch group
#define NGROUP (NSTEP / GSTEPS)  // 73

constexpr float LB_[NPAR] = {1.0f, 50.0f, 0.05f, 0.01f, 0.001f, 0.2f, 0.0f,
                             0.0f, -2.5f, 0.5f, 0.0f, 0.0f, 0.3f};
constexpr float UB_[NPAR] = {6.0f, 1000.0f, 0.9f, 0.5f, 0.2f, 1.0f, 10.0f,
                             100.0f, 2.5f, 10.0f, 0.1f, 0.2f, 5.0f};

__device__ __forceinline__ float fast_rcp(float x)  { return __builtin_amdgcn_rcpf(x); }
__device__ __forceinline__ float fast_exp2(float x) { return __builtin_amdgcn_exp2f(x); }
__device__ __forceinline__ float fast_log2(float x) { return __builtin_amdgcn_logf(x); }

__device__ __forceinline__ int mod13(int v) {
    int r = v % NPAR;
    if (r < 0) r += NPAR;
    return r;
}

// ---- 8-lane (mu) sum.
// Stages 1-2: DPP quad_perm xor1 / xor2 (unambiguous encodings).
// Stage 3: ds_swizzle xor-4, offset 0x101F per cdna4_isa.md common patterns
//          (round-2's row_ror:4 guess was WRONG: ror delivers lane i <- (i-4)%16,
//           i.e. lane 0 got quad-3's sum; swizzle xor-4 matches the passing
//           round-1 __shfl_xor(q,4) semantics).
// After the three adds, lanes with (lane&7)==0 hold the full 8-sum.
template <int CTRL>
__device__ __forceinline__ float dpp_xadd(float v) {
    int r = __builtin_amdgcn_update_dpp(0, __float_as_int(v), CTRL, 0xF, 0xF, true);
    return v + __int_as_float(r);
}
__device__ __forceinline__ float mu8_sum(float v) {
    v = dpp_xadd<0xB1>(v);   // quad_perm [1,0,3,2] : lane ^= 1
    v = dpp_xadd<0x4E>(v);   // quad_perm [2,3,0,1] : lane ^= 2
    int s = __builtin_amdgcn_ds_swizzle(__float_as_int(v), 0x101F); // lane ^= 4
    return v + __int_as_float(s);
}

// One HBV step. rcpFC / rcpLPFC supplied by caller (hoistable when FC/LP fixed).
__device__ __forceinline__ float hbv_step_core(
    float P_, float T_, float ET_,
    float BETA, float FC, float K0, float K1, float K2,
    float PERCc, float UZL, float TT, float CFMAX, float CFR, float CWH,
    float BETAET, float rcpFC, float rcpLPFC,
    float& SP, float& MW, float& SM, float& SUZ, float& SLZ)
{
    float dT    = T_ - TT;
    float RAIN  = (T_ >= TT) ? P_ : 0.f;
    float SNOW  = P_ - RAIN;
    SP += SNOW;
    float cm    = CFMAX * dT;
    float melt  = fminf(fmaxf(cm, 0.f), SP);
    MW += melt; SP -= melt;
    float refr  = fminf(fmaxf(-CFR * cm, 0.f), MW);
    SP += refr; MW -= refr;
    float tosoil = fmaxf(MW - CWH * SP, 0.f);
    MW -= tosoil;
    // (SM/FC)^BETA : exp2 output > 0 so lower clamp is dead; keep upper min.
    float soilw  = fminf(fast_exp2(BETA * fast_log2(SM * rcpFC)), 1.f);
    float rt     = RAIN + tosoil;
    float rech   = rt * soilw;
    SM += rt - rech;
    float excess = fmaxf(SM - FC, 0.f);
    SM -= excess;
    float evapf  = fminf(fast_exp2(BETAET * fast_log2(SM * rcpLPFC)), 1.f);
    float ETact  = fminf(SM, ET_ * evapf);
    SM = fmaxf(SM - ETact, PRECS);
    SUZ += rech + excess;
    float PERC = fminf(SUZ, PERCc);
    SUZ -= PERC;
    float Q0 = K0 * fmaxf(SUZ - UZL, 0.f);
    SUZ -= Q0;
    float Q1 = K1 * SUZ;
    SUZ -= Q1;
    SLZ += PERC;
    float Q2 = K2 * SLZ;
    SLZ -= Q2;
    return Q0 + Q1 + Q2;
}

// ---- Fast path: time-varying params are exactly {12 (BETAET), 0 (BETA)}.
// All 11 other params + their reciprocals hoisted out of the time loop.
__device__ __forceinline__ void hbv_fast_12_0(
    const float* __restrict__ x, const float* __restrict__ par,
    int staind, float* __restrict__ out, int g, int m)
{
    const unsigned cpar = (unsigned)g * PAR_GSTRIDE + (unsigned)m;
    const unsigned g3   = (unsigned)g * 3u;

    float fx[NPAR];
    const unsigned sbase = (unsigned)staind * PAR_TSTRIDE + cpar;
#pragma unroll
    for (int i = 0; i < NPAR; ++i)
        fx[i] = fmaf(par[sbase + (unsigned)i * 8u], UB_[i] - LB_[i], LB_[i]);
    const float FC = fx[1], K0 = fx[2], K1 = fx[3], K2 = fx[4], LP = fx[5],
                PERCc = fx[6], UZL = fx[7], TT = fx[8], CFMAX = fx[9],
                CFR = fx[10], CWH = fx[11];
    const float rcpFC   = fast_rcp(FC);
    const float rcpLPFC = fast_rcp(LP * FC);
    constexpr float lbB = LB_[0],  dvB = UB_[0]  - LB_[0];
    constexpr float lbE = LB_[12], dvE = UB_[12] - LB_[12];

    float bP[2][GSTEPS], bT[2][GSTEPS], bEv[2][GSTEPS];
    float bS0[2][GSTEPS], bS1[2][GSTEPS];
    float SP = 0.001f, MW = 0.001f, SM = 0.001f, SUZ = 0.001f, SLZ = 0.001f;

    auto load = [&](int b, int t0) {
#pragma unroll
        for (int j = 0; j < GSTEPS; ++j) {
            unsigned t  = (unsigned)(t0 + j);
            unsigned xo = t * X_TSTRIDE + g3;
            bP[b][j]  = x[xo];
            bT[b][j]  = x[xo + 1u];
            bEv[b][j] = x[xo + 2u];
            unsigned po = t * PAR_TSTRIDE + cpar;
            bS0[b][j] = par[po + 96u];  // param 12 (BETAET), *8
            bS1[b][j] = par[po + 0u];   // param 0  (BETA)
        }
    };
    auto compute = [&](int b, int t0) {
        float ql[GSTEPS];
#pragma unroll
        for (int j = 0; j < GSTEPS; ++j) {
            float BETAET = fmaf(bS0[b][j], dvE, lbE);
            float BETA   = fmaf(bS1[b][j], dvB, lbB);
            ql[j] = hbv_step_core(bP[b][j], bT[b][j], bEv[b][j],
                                  BETA, FC, K0, K1, K2, PERCc, UZL, TT, CFMAX,
                                  CFR, CWH, BETAET, rcpFC, rcpLPFC,
                                  SP, MW, SM, SUZ, SLZ);
        }
        // batched mu-mean + store: 10 independent reductions, latencies overlap
#pragma unroll
        for (int j = 0; j < GSTEPS; ++j) {
            float s = mu8_sum(ql[j]);
            if (m == 0)
                out[(unsigned)(t0 + j) * (unsigned)NGRID + (unsigned)g] = s * 0.125f;
        }
    };

    load(0, 0);
    for (int gp = 0; gp < NGROUP; gp += 2) {
        if (gp + 1 < NGROUP) load(1, (gp + 1) * GSTEPS);
        compute(0, gp * GSTEPS);
        if (gp + 2 < NGROUP) load(0, (gp + 2) * GSTEPS);
        if (gp + 1 < NGROUP) compute(1, (gp + 1) * GSTEPS);
    }
}

// ---- Generic NTD=2 body: selector-blend routing, per-step reciprocals.
__device__ void hbv_generic2(
    const float* __restrict__ x, const float* __restrict__ par,
    int staind, int idx0, int idx1, float* __restrict__ out, int g, int m)
{
    const unsigned cpar = (unsigned)g * PAR_GSTRIDE + (unsigned)m;
    const unsigned g3   = (unsigned)g * 3u;

    float lb0 = 0.f, dv0 = 0.f, lb1 = 0.f, dv1 = 0.f;
    float sel0[NPAR], sel1[NPAR];
#pragma unroll
    for (int i = 0; i < NPAR; ++i) {
        sel0[i] = (idx0 == i) ? 1.f : 0.f;
        sel1[i] = (idx1 == i && idx1 != idx0) ? 1.f : 0.f;
        if (idx0 == i) { lb0 = LB_[i]; dv0 = UB_[i] - LB_[i]; }
        if (idx1 == i) { lb1 = LB_[i]; dv1 = UB_[i] - LB_[i]; }
    }
    const unsigned off0 = (unsigned)idx0 * 8u, off1 = (unsigned)idx1 * 8u;

    float basep[NPAR];
    const unsigned sbase = (unsigned)staind * PAR_TSTRIDE + cpar;
#pragma unroll
    for (int i = 0; i < NPAR; ++i) {
        float fxv = fmaf(par[sbase + (unsigned)i * 8u], UB_[i] - LB_[i], LB_[i]);
        basep[i] = fxv * (1.f - sel0[i] - sel1[i]);
    }

    float bP[2][GSTEPS], bT[2][GSTEPS], bEv[2][GSTEPS];
    float bS0[2][GSTEPS], bS1[2][GSTEPS];
    float SP = 0.001f, MW = 0.001f, SM = 0.001f, SUZ = 0.001f, SLZ = 0.001f;

    auto load = [&](int b, int t0) {
#pragma unroll
        for (int j = 0; j < GSTEPS; ++j) {
            unsigned t  = (unsigned)(t0 + j);
            unsigned xo = t * X_TSTRIDE + g3;
            bP[b][j]  = x[xo];
            bT[b][j]  = x[xo + 1u];
            bEv[b][j] = x[xo + 2u];
            unsigned po = t * PAR_TSTRIDE + cpar;
            bS0[b][j] = par[po + off0];
            bS1[b][j] = par[po + off1];
        }
    };
    auto compute = [&](int b, int t0) {
        float ql[GSTEPS];
#pragma unroll
        for (int j = 0; j < GSTEPS; ++j) {
            float sv0 = fmaf(bS0[b][j], dv0, lb0);
            float sv1 = fmaf(bS1[b][j], dv1, lb1);
            float pr[NPAR];
#pragma unroll
            for (int i = 0; i < NPAR; ++i)
                pr[i] = fmaf(sel1[i], sv1, fmaf(sel0[i], sv0, basep[i]));
            float rcpFC   = fast_rcp(pr[1]);
            float rcpLPFC = fast_rcp(pr[5] * pr[1]);
            ql[j] = hbv_step_core(bP[b][j], bT[b][j], bEv[b][j],
                                  pr[0], pr[1], pr[2], pr[3], pr[4], pr[6],
                                  pr[7], pr[8], pr[9], pr[10], pr[11], pr[12],
                                  rcpFC, rcpLPFC, SP, MW, SM, SUZ, SLZ);
        }
#pragma unroll
        for (int j = 0; j < GSTEPS; ++j) {
            float s = mu8_sum(ql[j]);
            if (m == 0)
                out[(unsigned)(t0 + j) * (unsigned)NGRID + (unsigned)g] = s * 0.125f;
        }
    };

    load(0, 0);
    for (int gp = 0; gp < NGROUP; gp += 2) {
        if (gp + 1 < NGROUP) load(1, (gp + 1) * GSTEPS);
        compute(0, gp * GSTEPS);
        if (gp + 2 < NGROUP) load(0, (gp + 2) * GSTEPS);
        if (gp + 1 < NGROUP) compute(1, (gp + 1) * GSTEPS);
    }
}

__global__ __launch_bounds__(64, 1) void hbv_main(
    const float* __restrict__ x, const float* __restrict__ par,
    const int* __restrict__ staind_p, const int* __restrict__ tdlst_p,
    float* __restrict__ out)
{
    const int tid = blockIdx.x * 64 + threadIdx.x;   // grid*block == 8000 exactly
    const int g   = tid >> 3;
    const int m   = tid & 7;

    const int staind = __builtin_amdgcn_readfirstlane(staind_p[0]);
    const int idx0   = __builtin_amdgcn_readfirstlane(mod13(tdlst_p[0] - 1));
    const int idx1   = __builtin_amdgcn_readfirstlane(mod13(tdlst_p[1] - 1));

    if (idx0 == 12 && idx1 == 0)
        hbv_fast_12_0(x, par, staind, out, g, m);
    else
        hbv_generic2(x, par, staind, idx0, idx1, out, g, m);
}

// ---- Fallback for n_td != 2: per-step loads of all 13 params (stride trick).
__global__ __launch_bounds__(64, 1) void hbv_scan_generic(
    const float* __restrict__ x, const float* __restrict__ par,
    const int* __restrict__ staind_p, const int* __restrict__ tdlst_p,
    int n_td, float* __restrict__ out)
{
    const int tid = blockIdx.x * 64 + threadIdx.x;
    const int g   = tid >> 3;
    const int m   = tid & 7;
    if (g >= NGRID) return;

    const int staind    = staind_p[0];
    const unsigned cpar = (unsigned)g * PAR_GSTRIDE + (unsigned)m;
    const unsigned g3   = (unsigned)g * 3u;

    unsigned off[NPAR], st[NPAR];
#pragma unroll
    for (int i = 0; i < NPAR; ++i) {
        bool vr = false;
        for (int j = 0; j < n_td; ++j)
            if (mod13(tdlst_p[j] - 1) == i) vr = true;
        off[i] = (vr ? 0u : (unsigned)staind * PAR_TSTRIDE) + cpar + (unsigned)i * 8u;
        st[i]  = vr ? PAR_TSTRIDE : 0u;
    }

    float SP = 0.001f, MW = 0.001f, SM = 0.001f, SUZ = 0.001f, SLZ = 0.001f;
    for (int t = 0; t < NSTEP; ++t) {
        unsigned xo = (unsigned)t * X_TSTRIDE + g3;
        float P_ = x[xo], T_ = x[xo + 1u], E_ = x[xo + 2u];
        float pr[NPAR];
#pragma unroll
        for (int i = 0; i < NPAR; ++i) {
            pr[i] = fmaf(par[off[i]], UB_[i] - LB_[i], LB_[i]);
            off[i] += st[i];
        }
        float rcpFC   = fast_rcp(pr[1]);
        float rcpLPFC = fast_rcp(pr[5] * pr[1]);
        float q = hbv_step_core(P_, T_, E_, pr[0], pr[1], pr[2], pr[3], pr[4],
                                pr[6], pr[7], pr[8], pr[9], pr[10], pr[11],
                                pr[12], rcpFC, rcpLPFC, SP, MW, SM, SUZ, SLZ);
        float s = mu8_sum(q);
        if (m == 0) out[(unsigned)t * (unsigned)NGRID + (unsigned)g] = s * 0.125f;
    }
}

extern "C" void kernel_launch(void* const* d_in, const int* in_sizes, int n_in,
                              void* d_out, int out_size, void* d_ws, size_t ws_size,
                              hipStream_t stream) {
    const float* x      = (const float*)d_in[0];
    const float* par    = (const float*)d_in[1];
    const int*   staind = (const int*)d_in[2];
    const int*   tdlst  = (const int*)d_in[3];
    float*       out    = (float*)d_out;
    const int n_td = in_sizes[3];

    const int threads = NGRID * MU;                     // 8000
    const int block   = 64;
    const int grid    = (threads + block - 1) / block;  // 125

    if (n_td == 2)
        hbv_main<<<grid, block, 0, stream>>>(x, par, staind, tdlst, out);
    else
        hbv_scan_generic<<<grid, block, 0, stream>>>(x, par, staind, tdlst,
                                                     n_td, out);
}

// Round 4
// 430.920 us; speedup vs baseline: 1.2781x; 1.0899x over previous
//
#include <hip/hip_runtime.h>

#define NSTEP 730
#define NGRID 1000
#define MU    8
#define NPAR  13
#define PRECS 1e-5f

// parameters (NSTEP, NGRID, 13, MU): idx(t,g,i,m) = t*104000 + g*104 + i*8 + m
#define PAR_TSTRIDE 104000u
#define PAR_GSTRIDE 104u
// x (NSTEP, NGRID, 3): idx(t,g,c) = t*3000 + g*3 + c
#define X_TSTRIDE 3000u

#define GSTEPS 10                // group size for legacy generic paths
#define NGROUP (NSTEP / GSTEPS)  // 73

#define G5  5                    // fast-path group size (25 loads/group)
#define NG5 (NSTEP / G5)         // 146 = 48*3 + 2

constexpr float LB_[NPAR] = {1.0f, 50.0f, 0.05f, 0.01f, 0.001f, 0.2f, 0.0f,
                             0.0f, -2.5f, 0.5f, 0.0f, 0.0f, 0.3f};
constexpr float UB_[NPAR] = {6.0f, 1000.0f, 0.9f, 0.5f, 0.2f, 1.0f, 10.0f,
                             100.0f, 2.5f, 10.0f, 0.1f, 0.2f, 5.0f};

__device__ __forceinline__ float fast_rcp(float x)  { return __builtin_amdgcn_rcpf(x); }
__device__ __forceinline__ float fast_exp2(float x) { return __builtin_amdgcn_exp2f(x); }
__device__ __forceinline__ float fast_log2(float x) { return __builtin_amdgcn_logf(x); }

__device__ __forceinline__ int mod13(int v) {
    int r = v % NPAR;
    if (r < 0) r += NPAR;
    return r;
}

// ---- 8-lane (mu) sum: DPP quad_perm xor1/xor2 + ds_swizzle xor4 (0x101F).
// Verified correct in round 3. After the three adds every lane holds the 8-sum.
template <int CTRL>
__device__ __forceinline__ float dpp_xadd(float v) {
    int r = __builtin_amdgcn_update_dpp(0, __float_as_int(v), CTRL, 0xF, 0xF, true);
    return v + __int_as_float(r);
}
__device__ __forceinline__ float mu8_sum(float v) {
    v = dpp_xadd<0xB1>(v);   // quad_perm [1,0,3,2] : lane ^= 1
    v = dpp_xadd<0x4E>(v);   // quad_perm [2,3,0,1] : lane ^= 2
    int s = __builtin_amdgcn_ds_swizzle(__float_as_int(v), 0x101F); // lane ^= 4
    return v + __int_as_float(s);
}

// ---- Fast path: time-varying params are exactly {12 (BETAET), 0 (BETA)}.
// G=5 triple-buffered prefetch (<=50 outstanding loads, 2-group latency cover).
// Critical path per step reduced to: log2(SM) fma exp2 fma min log2 fma exp2
// min fma max  (~11 ops, 4 transcendental). All T/P-dependent prep batched.
__device__ __forceinline__ void hbv_fast_12_0(
    const float* __restrict__ x, const float* __restrict__ par,
    int staind, float* __restrict__ out, int g, int m)
{
    const unsigned cpar = (unsigned)g * PAR_GSTRIDE + (unsigned)m;
    const unsigned g3   = (unsigned)g * 3u;

    float fx[NPAR];
    const unsigned sbase = (unsigned)staind * PAR_TSTRIDE + cpar;
#pragma unroll
    for (int i = 0; i < NPAR; ++i)
        fx[i] = fmaf(par[sbase + (unsigned)i * 8u], UB_[i] - LB_[i], LB_[i]);
    const float FC = fx[1], K0 = fx[2], K1 = fx[3], K2 = fx[4], LP = fx[5],
                PERCc = fx[6], UZL = fx[7], TT = fx[8], CFMAX = fx[9],
                CFR = fx[10], CWH = fx[11];
    const float rcpFC    = fast_rcp(FC);
    const float rcpLPFC  = fast_rcp(LP * FC);
    const float l2rcpFC  = fast_log2(rcpFC);     // log2(1/FC)
    const float l2rcpLPF = fast_log2(rcpLPFC);   // log2(1/(LP*FC))
    const float CC       = CFR * CFMAX;
    constexpr float lbB = LB_[0],  dvB = UB_[0]  - LB_[0];
    constexpr float lbE = LB_[12], dvE = UB_[12] - LB_[12];

    // triple-buffered registers: 3 x 5 steps x 5 values = 75 VGPRs
    float bP[3][G5], bT[3][G5], bE[3][G5], b0[3][G5], b1[3][G5];
    float SP = 0.001f, MW = 0.001f, SM = 0.001f, SUZ = 0.001f, SLZ = 0.001f;

    auto load = [&](int b, int t0) {
#pragma unroll
        for (int j = 0; j < G5; ++j) {
            unsigned t  = (unsigned)(t0 + j);
            unsigned xo = t * X_TSTRIDE + g3;
            bP[b][j] = x[xo];
            bT[b][j] = x[xo + 1u];
            bE[b][j] = x[xo + 2u];
            unsigned po = t * PAR_TSTRIDE + cpar;
            b0[b][j] = par[po + 96u];  // param 12 (BETAET) * 8
            b1[b][j] = par[po + 0u];   // param 0  (BETA)
        }
    };

    auto compute = [&](int b, int t0) {
        // ---- batched state-independent prep (fills latency shadows)
        float RAINv[G5], SNOWv[G5], MAXCM[G5], MAXRF[G5], ETv[G5];
        float BETAv[G5], BETEv[G5], bbc[G5], ebc[G5];
#pragma unroll
        for (int j = 0; j < G5; ++j) {
            float Pj = bP[b][j], Tj = bT[b][j];
            float dT = Tj - TT;
            float RAIN = (dT >= 0.f) ? Pj : 0.f;
            RAINv[j] = RAIN;
            SNOWv[j] = Pj - RAIN;
            float cm = CFMAX * dT;
            MAXCM[j] = fmaxf(cm, 0.f);
            MAXRF[j] = fmaxf(-CC * dT, 0.f);
            ETv[j]   = bE[b][j];
            float BETAET = fmaf(b0[b][j], dvE, lbE);
            float BETA   = fmaf(b1[b][j], dvB, lbB);
            BETAv[j] = BETA;  BETEv[j] = BETAET;
            bbc[j] = BETA   * l2rcpFC;    // BETA*log2(1/FC)
            ebc[j] = BETAET * l2rcpLPF;   // BETAET*log2(1/(LP*FC))
        }
        // ---- serial 5-step chain
        float ql[G5];
#pragma unroll
        for (int j = 0; j < G5; ++j) {
            SP += SNOWv[j];
            float melt = fminf(MAXCM[j], SP);
            MW += melt; SP -= melt;
            float refr = fminf(MAXRF[j], MW);
            SP += refr; MW -= refr;
            float tosoil = fmaxf(fmaf(-CWH, SP, MW), 0.f);
            MW -= tosoil;
            float rt   = RAINv[j] + tosoil;
            float smrt = SM + rt;
            // soilw = (SM/FC)^BETA  (SM<=FC invariant -> <=1, clamp dead)
            float soilw = fast_exp2(fmaf(BETAv[j], fast_log2(SM), bbc[j]));
            float rech  = rt * soilw;
            float SM_mid = smrt - rech;
            float SM_ae  = fminf(SM_mid, FC);
            float excess = SM_mid - SM_ae;
            float evapf  = fminf(fast_exp2(fmaf(BETEv[j], fast_log2(SM_ae), ebc[j])), 1.f);
            // ETact=min(SM,ET*evapf); SM=max(SM-ETact,PRECS)  ==  below:
            SM = fmaxf(fmaf(-ETv[j], evapf, SM_ae), PRECS);
            SUZ += rech + excess;
            float PERC = fminf(SUZ, PERCc);
            float SUZp = SUZ - PERC;
            float Q0   = K0 * fmaxf(SUZp - UZL, 0.f);
            float SUZq = SUZp - Q0;
            float Q1   = K1 * SUZq;
            SUZ = SUZq - Q1;
            SLZ += PERC;
            float Q2 = K2 * SLZ;
            SLZ -= Q2;
            ql[j] = (Q0 + Q1) + Q2;
        }
        // ---- batched mu-mean + predicated store
#pragma unroll
        for (int j = 0; j < G5; ++j) ql[j] = mu8_sum(ql[j]);
        if (m == 0) {
#pragma unroll
            for (int j = 0; j < G5; ++j)
                out[(unsigned)(t0 + j) * (unsigned)NGRID + (unsigned)g] = ql[j] * 0.125f;
        }
    };

    // 146 groups = 48*3 + 2; distance-2 prefetch, <=2 load batches in flight.
    load(0, 0);
    load(1, G5);
    int grp = 0;
    for (int it = 0; it < 48; ++it, grp += 3) {
        load(2, (grp + 2) * G5); compute(0, grp * G5);
        load(0, (grp + 3) * G5); compute(1, (grp + 1) * G5);
        load(1, (grp + 4) * G5); compute(2, (grp + 2) * G5);
    }
    // grp == 144; groups 144 (buf0) and 145 (buf1) already loaded.
    compute(0, 144 * G5);
    compute(1, 145 * G5);
}

// One HBV step (legacy helper for generic paths). rcpFC/rcpLPFC from caller.
__device__ __forceinline__ float hbv_step_core(
    float P_, float T_, float ET_,
    float BETA, float FC, float K0, float K1, float K2,
    float PERCc, float UZL, float TT, float CFMAX, float CFR, float CWH,
    float BETAET, float rcpFC, float rcpLPFC,
    float& SP, float& MW, float& SM, float& SUZ, float& SLZ)
{
    float dT    = T_ - TT;
    float RAIN  = (T_ >= TT) ? P_ : 0.f;
    float SNOW  = P_ - RAIN;
    SP += SNOW;
    float cm    = CFMAX * dT;
    float melt  = fminf(fmaxf(cm, 0.f), SP);
    MW += melt; SP -= melt;
    float refr  = fminf(fmaxf(-CFR * cm, 0.f), MW);
    SP += refr; MW -= refr;
    float tosoil = fmaxf(MW - CWH * SP, 0.f);
    MW -= tosoil;
    float soilw  = fminf(fast_exp2(BETA * fast_log2(SM * rcpFC)), 1.f);
    float rt     = RAIN + tosoil;
    float rech   = rt * soilw;
    SM += rt - rech;
    float excess = fmaxf(SM - FC, 0.f);
    SM -= excess;
    float evapf  = fminf(fast_exp2(BETAET * fast_log2(SM * rcpLPFC)), 1.f);
    float ETact  = fminf(SM, ET_ * evapf);
    SM = fmaxf(SM - ETact, PRECS);
    SUZ += rech + excess;
    float PERC = fminf(SUZ, PERCc);
    SUZ -= PERC;
    float Q0 = K0 * fmaxf(SUZ - UZL, 0.f);
    SUZ -= Q0;
    float Q1 = K1 * SUZ;
    SUZ -= Q1;
    SLZ += PERC;
    float Q2 = K2 * SLZ;
    SLZ -= Q2;
    return Q0 + Q1 + Q2;
}

// ---- Generic NTD=2 body (unchanged from round 3, known-correct).
__device__ void hbv_generic2(
    const float* __restrict__ x, const float* __restrict__ par,
    int staind, int idx0, int idx1, float* __restrict__ out, int g, int m)
{
    const unsigned cpar = (unsigned)g * PAR_GSTRIDE + (unsigned)m;
    const unsigned g3   = (unsigned)g * 3u;

    float lb0 = 0.f, dv0 = 0.f, lb1 = 0.f, dv1 = 0.f;
    float sel0[NPAR], sel1[NPAR];
#pragma unroll
    for (int i = 0; i < NPAR; ++i) {
        sel0[i] = (idx0 == i) ? 1.f : 0.f;
        sel1[i] = (idx1 == i && idx1 != idx0) ? 1.f : 0.f;
        if (idx0 == i) { lb0 = LB_[i]; dv0 = UB_[i] - LB_[i]; }
        if (idx1 == i) { lb1 = LB_[i]; dv1 = UB_[i] - LB_[i]; }
    }
    const unsigned off0 = (unsigned)idx0 * 8u, off1 = (unsigned)idx1 * 8u;

    float basep[NPAR];
    const unsigned sbase = (unsigned)staind * PAR_TSTRIDE + cpar;
#pragma unroll
    for (int i = 0; i < NPAR; ++i) {
        float fxv = fmaf(par[sbase + (unsigned)i * 8u], UB_[i] - LB_[i], LB_[i]);
        basep[i] = fxv * (1.f - sel0[i] - sel1[i]);
    }

    float bP[2][GSTEPS], bT[2][GSTEPS], bEv[2][GSTEPS];
    float bS0[2][GSTEPS], bS1[2][GSTEPS];
    float SP = 0.001f, MW = 0.001f, SM = 0.001f, SUZ = 0.001f, SLZ = 0.001f;

    auto load = [&](int b, int t0) {
#pragma unroll
        for (int j = 0; j < GSTEPS; ++j) {
            unsigned t  = (unsigned)(t0 + j);
            unsigned xo = t * X_TSTRIDE + g3;
            bP[b][j]  = x[xo];
            bT[b][j]  = x[xo + 1u];
            bEv[b][j] = x[xo + 2u];
            unsigned po = t * PAR_TSTRIDE + cpar;
            bS0[b][j] = par[po + off0];
            bS1[b][j] = par[po + off1];
        }
    };
    auto compute = [&](int b, int t0) {
        float ql[GSTEPS];
#pragma unroll
        for (int j = 0; j < GSTEPS; ++j) {
            float sv0 = fmaf(bS0[b][j], dv0, lb0);
            float sv1 = fmaf(bS1[b][j], dv1, lb1);
            float pr[NPAR];
#pragma unroll
            for (int i = 0; i < NPAR; ++i)
                pr[i] = fmaf(sel1[i], sv1, fmaf(sel0[i], sv0, basep[i]));
            float rcpFC   = fast_rcp(pr[1]);
            float rcpLPFC = fast_rcp(pr[5] * pr[1]);
            ql[j] = hbv_step_core(bP[b][j], bT[b][j], bEv[b][j],
                                  pr[0], pr[1], pr[2], pr[3], pr[4], pr[6],
                                  pr[7], pr[8], pr[9], pr[10], pr[11], pr[12],
                                  rcpFC, rcpLPFC, SP, MW, SM, SUZ, SLZ);
        }
#pragma unroll
        for (int j = 0; j < GSTEPS; ++j) {
            float s = mu8_sum(ql[j]);
            if (m == 0)
                out[(unsigned)(t0 + j) * (unsigned)NGRID + (unsigned)g] = s * 0.125f;
        }
    };

    load(0, 0);
    for (int gp = 0; gp < NGROUP; gp += 2) {
        if (gp + 1 < NGROUP) load(1, (gp + 1) * GSTEPS);
        compute(0, gp * GSTEPS);
        if (gp + 2 < NGROUP) load(0, (gp + 2) * GSTEPS);
        if (gp + 1 < NGROUP) compute(1, (gp + 1) * GSTEPS);
    }
}

__global__ __launch_bounds__(64, 1) void hbv_main(
    const float* __restrict__ x, const float* __restrict__ par,
    const int* __restrict__ staind_p, const int* __restrict__ tdlst_p,
    float* __restrict__ out)
{
    const int tid = blockIdx.x * 64 + threadIdx.x;   // grid*block == 8000 exactly
    const int g   = tid >> 3;
    const int m   = tid & 7;

    const int staind = __builtin_amdgcn_readfirstlane(staind_p[0]);
    const int idx0   = __builtin_amdgcn_readfirstlane(mod13(tdlst_p[0] - 1));
    const int idx1   = __builtin_amdgcn_readfirstlane(mod13(tdlst_p[1] - 1));

    if (idx0 == 12 && idx1 == 0)
        hbv_fast_12_0(x, par, staind, out, g, m);
    else
        hbv_generic2(x, par, staind, idx0, idx1, out, g, m);
}

// ---- Fallback for n_td != 2 (unchanged from round 3).
__global__ __launch_bounds__(64, 1) void hbv_scan_generic(
    const float* __restrict__ x, const float* __restrict__ par,
    const int* __restrict__ staind_p, const int* __restrict__ tdlst_p,
    int n_td, float* __restrict__ out)
{
    const int tid = blockIdx.x * 64 + threadIdx.x;
    const int g   = tid >> 3;
    const int m   = tid & 7;
    if (g >= NGRID) return;

    const int staind    = staind_p[0];
    const unsigned cpar = (unsigned)g * PAR_GSTRIDE + (unsigned)m;
    const unsigned g3   = (unsigned)g * 3u;

    unsigned off[NPAR], st[NPAR];
#pragma unroll
    for (int i = 0; i < NPAR; ++i) {
        bool vr = false;
        for (int j = 0; j < n_td; ++j)
            if (mod13(tdlst_p[j] - 1) == i) vr = true;
        off[i] = (vr ? 0u : (unsigned)staind * PAR_TSTRIDE) + cpar + (unsigned)i * 8u;
        st[i]  = vr ? PAR_TSTRIDE : 0u;
    }

    float SP = 0.001f, MW = 0.001f, SM = 0.001f, SUZ = 0.001f, SLZ = 0.001f;
    for (int t = 0; t < NSTEP; ++t) {
        unsigned xo = (unsigned)t * X_TSTRIDE + g3;
        float P_ = x[xo], T_ = x[xo + 1u], E_ = x[xo + 2u];
        float pr[NPAR];
#pragma unroll
        for (int i = 0; i < NPAR; ++i) {
            pr[i] = fmaf(par[off[i]], UB_[i] - LB_[i], LB_[i]);
            off[i] += st[i];
        }
        float rcpFC   = fast_rcp(pr[1]);
        float rcpLPFC = fast_rcp(pr[5] * pr[1]);
        float q = hbv_step_core(P_, T_, E_, pr[0], pr[1], pr[2], pr[3], pr[4],
                                pr[6], pr[7], pr[8], pr[9], pr[10], pr[11],
                                pr[12], rcpFC, rcpLPFC, SP, MW, SM, SUZ, SLZ);
        float s = mu8_sum(q);
        if (m == 0) out[(unsigned)t * (unsigned)NGRID + (unsigned)g] = s * 0.125f;
    }
}

extern "C" void kernel_launch(void* const* d_in, const int* in_sizes, int n_in,
                              void* d_out, int out_size, void* d_ws, size_t ws_size,
                              hipStream_t stream) {
    const float* x      = (const float*)d_in[0];
    const float* par    = (const float*)d_in[1];
    const int*   staind = (const int*)d_in[2];
    const int*   tdlst  = (const int*)d_in[3];
    float*       out    = (float*)d_out;
    const int n_td = in_sizes[3];

    const int threads = NGRID * MU;                     // 8000
    const int block   = 64;
    const int grid    = (threads + block - 1) / block;  // 125

    if (n_td == 2)
        hbv_main<<<grid, block, 0, stream>>>(x, par, staind, tdlst, out);
    else
        hbv_scan_generic<<<grid, block, 0, stream>>>(x, par, staind, tdlst,
                                                     n_td, out);
}

// Round 5
// 420.679 us; speedup vs baseline: 1.3092x; 1.0243x over previous
//
#include <hip/hip_runtime.h>

#define NSTEP 730
#define NGRID 1000
#define NPAR  13
#define PRECS 1e-5f

// parameters (NSTEP, NGRID, 13, MU=8): idx(t,g,i,m) = t*104000 + g*104 + i*8 + m
#define PAR_TSTRIDE 104000u
#define PAR_GSTRIDE 104u
// x (NSTEP, NGRID, 3): idx(t,g,c) = t*3000 + g*3 + c
#define X_TSTRIDE 3000u

#define G10   10                 // steps per group
#define NG10  73                 // 730/10 groups

#define GSTEPS 10                // legacy generic path group size
#define NGROUP 73

// LDS layout (floats): prep[2][10][9][64] = 11520, then ql[2][10][64] = 1280.
#define LDS_PREP_BUF 5760        // floats per prep buffer
#define LDS_QL_BASE  11520
#define LDS_QL_BUF   640
#define LDS_TOTAL    12800       // 51200 bytes

constexpr float LB_[NPAR] = {1.0f, 50.0f, 0.05f, 0.01f, 0.001f, 0.2f, 0.0f,
                             0.0f, -2.5f, 0.5f, 0.0f, 0.0f, 0.3f};
constexpr float UB_[NPAR] = {6.0f, 1000.0f, 0.9f, 0.5f, 0.2f, 1.0f, 10.0f,
                             100.0f, 2.5f, 10.0f, 0.1f, 0.2f, 5.0f};

__device__ __forceinline__ float fast_rcp(float x)  { return __builtin_amdgcn_rcpf(x); }
__device__ __forceinline__ float fast_exp2(float x) { return __builtin_amdgcn_exp2f(x); }
__device__ __forceinline__ float fast_log2(float x) { return __builtin_amdgcn_logf(x); }

__device__ __forceinline__ int mod13(int v) {
    int r = v % NPAR;
    if (r < 0) r += NPAR;
    return r;
}

// ---- 8-lane (mu) sum: DPP quad_perm xor1/xor2 + ds_swizzle xor4 (0x101F).
// Verified correct in rounds 3-4.
template <int CTRL>
__device__ __forceinline__ float dpp_xadd(float v) {
    int r = __builtin_amdgcn_update_dpp(0, __float_as_int(v), CTRL, 0xF, 0xF, true);
    return v + __int_as_float(r);
}
__device__ __forceinline__ float mu8_sum(float v) {
    v = dpp_xadd<0xB1>(v);   // lane ^= 1
    v = dpp_xadd<0x4E>(v);   // lane ^= 2
    int s = __builtin_amdgcn_ds_swizzle(__float_as_int(v), 0x101F); // lane ^= 4
    return v + __int_as_float(s);
}

// One HBV step (legacy helper for generic paths).
__device__ __forceinline__ float hbv_step_core(
    float P_, float T_, float ET_,
    float BETA, float FC, float K0, float K1, float K2,
    float PERCc, float UZL, float TT, float CFMAX, float CFR, float CWH,
    float BETAET, float rcpFC, float rcpLPFC,
    float& SP, float& MW, float& SM, float& SUZ, float& SLZ)
{
    float dT    = T_ - TT;
    float RAIN  = (T_ >= TT) ? P_ : 0.f;
    float SNOW  = P_ - RAIN;
    SP += SNOW;
    float cm    = CFMAX * dT;
    float melt  = fminf(fmaxf(cm, 0.f), SP);
    MW += melt; SP -= melt;
    float refr  = fminf(fmaxf(-CFR * cm, 0.f), MW);
    SP += refr; MW -= refr;
    float tosoil = fmaxf(MW - CWH * SP, 0.f);
    MW -= tosoil;
    float soilw  = fminf(fast_exp2(BETA * fast_log2(SM * rcpFC)), 1.f);
    float rt     = RAIN + tosoil;
    float rech   = rt * soilw;
    SM += rt - rech;
    float excess = fmaxf(SM - FC, 0.f);
    SM -= excess;
    float evapf  = fminf(fast_exp2(BETAET * fast_log2(SM * rcpLPFC)), 1.f);
    float ETact  = fminf(SM, ET_ * evapf);
    SM = fmaxf(SM - ETact, PRECS);
    SUZ += rech + excess;
    float PERC = fminf(SUZ, PERCc);
    SUZ -= PERC;
    float Q0 = K0 * fmaxf(SUZ - UZL, 0.f);
    SUZ -= Q0;
    float Q1 = K1 * SUZ;
    SUZ -= Q1;
    SLZ += PERC;
    float Q2 = K2 * SLZ;
    SLZ -= Q2;
    return Q0 + Q1 + Q2;
}

// ---- Generic NTD=2 single-wave body (round-3-verified fallback).
__device__ void hbv_generic2(
    const float* __restrict__ x, const float* __restrict__ par,
    int staind, int idx0, int idx1, float* __restrict__ out, int g, int m)
{
    const unsigned cpar = (unsigned)g * PAR_GSTRIDE + (unsigned)m;
    const unsigned g3   = (unsigned)g * 3u;

    float lb0 = 0.f, dv0 = 0.f, lb1 = 0.f, dv1 = 0.f;
    float sel0[NPAR], sel1[NPAR];
#pragma unroll
    for (int i = 0; i < NPAR; ++i) {
        sel0[i] = (idx0 == i) ? 1.f : 0.f;
        sel1[i] = (idx1 == i && idx1 != idx0) ? 1.f : 0.f;
        if (idx0 == i) { lb0 = LB_[i]; dv0 = UB_[i] - LB_[i]; }
        if (idx1 == i) { lb1 = LB_[i]; dv1 = UB_[i] - LB_[i]; }
    }
    const unsigned off0 = (unsigned)idx0 * 8u, off1 = (unsigned)idx1 * 8u;

    float basep[NPAR];
    const unsigned sbase = (unsigned)staind * PAR_TSTRIDE + cpar;
#pragma unroll
    for (int i = 0; i < NPAR; ++i) {
        float fxv = fmaf(par[sbase + (unsigned)i * 8u], UB_[i] - LB_[i], LB_[i]);
        basep[i] = fxv * (1.f - sel0[i] - sel1[i]);
    }

    float bP[2][GSTEPS], bT[2][GSTEPS], bEv[2][GSTEPS];
    float bS0[2][GSTEPS], bS1[2][GSTEPS];
    float SP = 0.001f, MW = 0.001f, SM = 0.001f, SUZ = 0.001f, SLZ = 0.001f;

    auto load = [&](int b, int t0) {
#pragma unroll
        for (int j = 0; j < GSTEPS; ++j) {
            unsigned t  = (unsigned)(t0 + j);
            unsigned xo = t * X_TSTRIDE + g3;
            bP[b][j]  = x[xo];
            bT[b][j]  = x[xo + 1u];
            bEv[b][j] = x[xo + 2u];
            unsigned po = t * PAR_TSTRIDE + cpar;
            bS0[b][j] = par[po + off0];
            bS1[b][j] = par[po + off1];
        }
    };
    auto compute = [&](int b, int t0) {
        float ql[GSTEPS];
#pragma unroll
        for (int j = 0; j < GSTEPS; ++j) {
            float sv0 = fmaf(bS0[b][j], dv0, lb0);
            float sv1 = fmaf(bS1[b][j], dv1, lb1);
            float pr[NPAR];
#pragma unroll
            for (int i = 0; i < NPAR; ++i)
                pr[i] = fmaf(sel1[i], sv1, fmaf(sel0[i], sv0, basep[i]));
            float rcpFC   = fast_rcp(pr[1]);
            float rcpLPFC = fast_rcp(pr[5] * pr[1]);
            ql[j] = hbv_step_core(bP[b][j], bT[b][j], bEv[b][j],
                                  pr[0], pr[1], pr[2], pr[3], pr[4], pr[6],
                                  pr[7], pr[8], pr[9], pr[10], pr[11], pr[12],
                                  rcpFC, rcpLPFC, SP, MW, SM, SUZ, SLZ);
        }
#pragma unroll
        for (int j = 0; j < GSTEPS; ++j) {
            float s = mu8_sum(ql[j]);
            if (m == 0)
                out[(unsigned)(t0 + j) * (unsigned)NGRID + (unsigned)g] = s * 0.125f;
        }
    };

    load(0, 0);
    for (int gp = 0; gp < NGROUP; gp += 2) {
        if (gp + 1 < NGROUP) load(1, (gp + 1) * GSTEPS);
        compute(0, gp * GSTEPS);
        if (gp + 2 < NGROUP) load(0, (gp + 2) * GSTEPS);
        if (gp + 1 < NGROUP) compute(1, (gp + 1) * GSTEPS);
    }
}

// ==== Producer/consumer kernel: block = 128 (wave 0 = producer, wave 1 =
// consumer). Fast path only for tdlst -> {12, 0}; otherwise wave 0 runs the
// generic single-wave body (no barriers on that path, grid-uniform branch).
__global__ __launch_bounds__(128, 1) void hbv_pc(
    const float* __restrict__ x, const float* __restrict__ par,
    const int* __restrict__ staind_p, const int* __restrict__ tdlst_p,
    float* __restrict__ out)
{
    __shared__ float lds[LDS_TOTAL];

    const int lane  = threadIdx.x & 63;
    const int wave  = threadIdx.x >> 6;
    const int chain = blockIdx.x * 64 + lane;   // 125 blocks * 64 = 8000 chains
    const int g = chain >> 3;
    const int m = chain & 7;

    const int staind = __builtin_amdgcn_readfirstlane(staind_p[0]);
    const int idx0   = __builtin_amdgcn_readfirstlane(mod13(tdlst_p[0] - 1));
    const int idx1   = __builtin_amdgcn_readfirstlane(mod13(tdlst_p[1] - 1));

    if (!(idx0 == 12 && idx1 == 0)) {           // grid-uniform branch
        if (wave == 0) hbv_generic2(x, par, staind, idx0, idx1, out, g, m);
        return;
    }

    const unsigned cpar = (unsigned)g * PAR_GSTRIDE + (unsigned)m;
    const unsigned g3   = (unsigned)g * 3u;

    // staind-row params, scaled (both waves need subsets; load all 13 once).
    float fx[NPAR];
    const unsigned sbase = (unsigned)staind * PAR_TSTRIDE + cpar;
#pragma unroll
    for (int i = 0; i < NPAR; ++i)
        fx[i] = fmaf(par[sbase + (unsigned)i * 8u], UB_[i] - LB_[i], LB_[i]);

    if (wave == 0) {
        // ================= PRODUCER =================
        const float TT = fx[8], CFMAX = fx[9], CC = fx[10] * fx[9];
        const float rcpFC    = fast_rcp(fx[1]);
        const float rcpLPFC  = fast_rcp(fx[5] * fx[1]);
        const float l2rcpFC  = fast_log2(rcpFC);
        const float l2rcpLPF = fast_log2(rcpLPFC);
        constexpr float lbB = LB_[0],  dvB = UB_[0]  - LB_[0];
        constexpr float lbE = LB_[12], dvE = UB_[12] - LB_[12];

        // triple-buffered VGPR prefetch: 3 bufs x 10 steps x 5 vals
        float vP[3][G10], vT[3][G10], vE[3][G10], v0[3][G10], v1[3][G10];

        auto gload = [&](int b, int grp) {
            int t0 = grp * G10;
#pragma unroll
            for (int j = 0; j < G10; ++j) {
                unsigned t  = (unsigned)(t0 + j);
                unsigned xo = t * X_TSTRIDE + g3;
                vP[b][j] = x[xo];
                vT[b][j] = x[xo + 1u];
                vE[b][j] = x[xo + 2u];
                unsigned po = t * PAR_TSTRIDE + cpar;
                v0[b][j] = par[po + 96u];  // param 12 (BETAET) raw
                v1[b][j] = par[po];        // param 0  (BETA) raw
            }
        };
        auto prep = [&](int b, int dbuf) {
            float* pw = &lds[dbuf * LDS_PREP_BUF + lane];
#pragma unroll
            for (int j = 0; j < G10; ++j) {
                float Pj = vP[b][j], Tj = vT[b][j];
                float dT   = Tj - TT;
                float RAIN = (dT >= 0.f) ? Pj : 0.f;
                float BETAET = fmaf(v0[b][j], dvE, lbE);
                float BETA   = fmaf(v1[b][j], dvB, lbB);
                pw[(j * 9 + 0) * 64] = Pj - RAIN;             // SNOW
                pw[(j * 9 + 1) * 64] = fmaxf(CFMAX * dT, 0.f); // MAXCM
                pw[(j * 9 + 2) * 64] = fmaxf(-CC * dT, 0.f);   // MAXRF
                pw[(j * 9 + 3) * 64] = RAIN;
                pw[(j * 9 + 4) * 64] = vE[b][j];               // ET
                pw[(j * 9 + 5) * 64] = BETA * l2rcpFC;         // bbc
                pw[(j * 9 + 6) * 64] = BETAET * l2rcpLPF;      // ebc
                pw[(j * 9 + 7) * 64] = BETA;
                pw[(j * 9 + 8) * 64] = BETAET;
            }
        };
        auto red = [&](int sbuf, int grp) {
            const float* qb = &lds[LDS_QL_BASE + sbuf * LDS_QL_BUF + lane];
            float s[G10];
#pragma unroll
            for (int j = 0; j < G10; ++j) s[j] = mu8_sum(qb[j * 64]);
            if (m == 0) {
#pragma unroll
                for (int j = 0; j < G10; ++j)
                    out[(unsigned)(grp * G10 + j) * (unsigned)NGRID + (unsigned)g]
                        = s[j] * 0.125f;
            }
        };

#define PHASE(kk, BL, BP)                                   \
        {                                                   \
            __syncthreads();                                \
            if ((kk) + 3 < NG10) gload(BL, (kk) + 3);       \
            if ((kk) + 1 < NG10) prep(BP, ((kk) + 1) & 1);  \
            if ((kk) >= 1) red(((kk) - 1) & 1, (kk) - 1);   \
        }

        gload(0, 0); gload(1, 1); gload(2, 2);
        prep(0, 0);                      // group 0 -> lds buf 0
        int k = 0;
        for (int t = 0; t < 24; ++t) {   // k = 0..71, vgpr-buf pattern 0,1,2
            PHASE(k, 0, 1); ++k;
            PHASE(k, 1, 2); ++k;
            PHASE(k, 2, 0); ++k;
        }
        PHASE(k, 0, 1);                  // k == 72: only red(71) survives guards
        __syncthreads();
        red(0, 72);                      // 72 & 1 == 0
#undef PHASE
    } else {
        // ================= CONSUMER =================
        const float FC = fx[1], K0 = fx[2], K1 = fx[3], K2 = fx[4],
                    PERCc = fx[6], UZL = fx[7], CWH = fx[11];
        float SP = 0.001f, MW = 0.001f, SM = 0.001f, SUZ = 0.001f, SLZ = 0.001f;

        for (int k = 0; k < NG10; ++k) {
            __syncthreads();
            const float* pr = &lds[(k & 1) * LDS_PREP_BUF + lane];
            float* qw = &lds[LDS_QL_BASE + (k & 1) * LDS_QL_BUF + lane];
#pragma unroll
            for (int j = 0; j < G10; ++j) {
                float SNOW   = pr[(j * 9 + 0) * 64];
                float MAXCM  = pr[(j * 9 + 1) * 64];
                float MAXRF  = pr[(j * 9 + 2) * 64];
                float RAIN   = pr[(j * 9 + 3) * 64];
                float ET     = pr[(j * 9 + 4) * 64];
                float bbc    = pr[(j * 9 + 5) * 64];
                float ebc    = pr[(j * 9 + 6) * 64];
                float BETA   = pr[(j * 9 + 7) * 64];
                float BETAET = pr[(j * 9 + 8) * 64];

                SP += SNOW;
                float melt = fminf(MAXCM, SP);
                MW += melt; SP -= melt;
                float refr = fminf(MAXRF, MW);
                SP += refr; MW -= refr;
                float tosoil = fmaxf(fmaf(-CWH, SP, MW), 0.f);
                MW -= tosoil;
                float rt    = RAIN + tosoil;
                float soilw = fast_exp2(fmaf(BETA, fast_log2(SM), bbc));
                float rech  = rt * soilw;
                float SM_mid = SM + rt - rech;
                float SM_ae  = fminf(SM_mid, FC);
                float excess = SM_mid - SM_ae;
                float evapf  = fminf(fast_exp2(fmaf(BETAET, fast_log2(SM_ae), ebc)), 1.f);
                SM = fmaxf(fmaf(-ET, evapf, SM_ae), PRECS);
                SUZ += rech + excess;
                float PERC = fminf(SUZ, PERCc);
                float SUZp = SUZ - PERC;
                float Q0   = K0 * fmaxf(SUZp - UZL, 0.f);
                float SUZq = SUZp - Q0;
                float Q1   = K1 * SUZq;
                SUZ = SUZq - Q1;
                SLZ += PERC;
                float Q2 = K2 * SLZ;
                SLZ -= Q2;
                qw[j * 64] = (Q0 + Q1) + Q2;
            }
        }
        __syncthreads();                 // matches producer's epilogue barrier
    }
}

// ---- Fallback kernel for n_td != 2 (unchanged, round-3-verified).
__global__ __launch_bounds__(64, 1) void hbv_scan_generic(
    const float* __restrict__ x, const float* __restrict__ par,
    const int* __restrict__ staind_p, const int* __restrict__ tdlst_p,
    int n_td, float* __restrict__ out)
{
    const int tid = blockIdx.x * 64 + threadIdx.x;
    const int g   = tid >> 3;
    const int m   = tid & 7;
    if (g >= NGRID) return;

    const int staind    = staind_p[0];
    const unsigned cpar = (unsigned)g * PAR_GSTRIDE + (unsigned)m;
    const unsigned g3   = (unsigned)g * 3u;

    unsigned off[NPAR], st[NPAR];
#pragma unroll
    for (int i = 0; i < NPAR; ++i) {
        bool vr = false;
        for (int j = 0; j < n_td; ++j)
            if (mod13(tdlst_p[j] - 1) == i) vr = true;
        off[i] = (vr ? 0u : (unsigned)staind * PAR_TSTRIDE) + cpar + (unsigned)i * 8u;
        st[i]  = vr ? PAR_TSTRIDE : 0u;
    }

    float SP = 0.001f, MW = 0.001f, SM = 0.001f, SUZ = 0.001f, SLZ = 0.001f;
    for (int t = 0; t < NSTEP; ++t) {
        unsigned xo = (unsigned)t * X_TSTRIDE + g3;
        float P_ = x[xo], T_ = x[xo + 1u], E_ = x[xo + 2u];
        float pr[NPAR];
#pragma unroll
        for (int i = 0; i < NPAR; ++i) {
            pr[i] = fmaf(par[off[i]], UB_[i] - LB_[i], LB_[i]);
            off[i] += st[i];
        }
        float rcpFC   = fast_rcp(pr[1]);
        float rcpLPFC = fast_rcp(pr[5] * pr[1]);
        float q = hbv_step_core(P_, T_, E_, pr[0], pr[1], pr[2], pr[3], pr[4],
                                pr[6], pr[7], pr[8], pr[9], pr[10], pr[11],
                                pr[12], rcpFC, rcpLPFC, SP, MW, SM, SUZ, SLZ);
        float s = mu8_sum(q);
        if (m == 0) out[(unsigned)t * (unsigned)NGRID + (unsigned)g] = s * 0.125f;
    }
}

extern "C" void kernel_launch(void* const* d_in, const int* in_sizes, int n_in,
                              void* d_out, int out_size, void* d_ws, size_t ws_size,
                              hipStream_t stream) {
    const float* x      = (const float*)d_in[0];
    const float* par    = (const float*)d_in[1];
    const int*   staind = (const int*)d_in[2];
    const int*   tdlst  = (const int*)d_in[3];
    float*       out    = (float*)d_out;
    const int n_td = in_sizes[3];

    if (n_td == 2) {
        hbv_pc<<<125, 128, 0, stream>>>(x, par, staind, tdlst, out);
    } else {
        hbv_scan_generic<<<125, 64, 0, stream>>>(x, par, staind, tdlst,
                                                 n_td, out);
    }
}